// Round 14
// baseline (52.355 us; speedup 1.0000x reference)
//
#include <hip/hip_runtime.h>
#include <cstdint>
#include <cstddef>

typedef unsigned short u16;
typedef __attribute__((ext_vector_type(8))) short short8;
typedef __attribute__((ext_vector_type(4))) float f32x4;

__device__ __forceinline__ u16 f2bf(float f){
  union { float f; unsigned u; } c; c.f = f;
  unsigned u = c.u;
  u += 0x7fffu + ((u >> 16) & 1u);   // RNE
  return (u16)(u >> 16);
}
__device__ __forceinline__ unsigned pk2(float a, float b){
  union { float f; unsigned u; } ca, cb; ca.f = a; cb.f = b;
  return ((ca.u + 0x8000u) >> 16) | ((cb.u + 0x8000u) & 0xFFFF0000u);
}

// xT2 layout: [b][row 0..65][col 0..65][128ci] bf16, interior at (h+1, w+1).
#define XB_STRIDE 557568   // 66*66*128 (u16 elements)
#define XR_STRIDE 8448     // 66*128

// wcomb layout (u16): b*147456 + ((tap*4+q)<<12) + (co<<5) + ciq
//   where ci = q*32 + ciq. One (tap,q) slab = 128co x 32ci = 8KB, linear.

// direct-to-LDS 16B async copy
#define GLD_LDS(gsrc, ldst) \
  __builtin_amdgcn_global_load_lds((const __attribute__((address_space(1))) void*)(gsrc), \
                                   (__attribute__((address_space(3))) void*)(ldst), 16, 0, 0)

// raw barrier WITHOUT the implicit vmcnt(0) drain of __syncthreads()
#define BAR { asm volatile("s_waitcnt lgkmcnt(0)" ::: "memory"); \
              __builtin_amdgcn_s_barrier(); }
#define WAIT_VM(N) asm volatile("s_waitcnt vmcnt(" #N ")" ::: "memory")

// ---------------------------------------------------------------------------
// Kernel 1: transpose x -> padded xT2 bf16 + SE pool partials.
// x reads are NON-TEMPORAL via ext-vector f32x4 (read-once stream; keeps the
// L2-homed xT2 victim lines resident for conv). grid 1024, b = bid&15.
// ---------------------------------------------------------------------------
__global__ __launch_bounds__(256) void xpose_pool(
    const float* __restrict__ x, u16* __restrict__ xT2, float* __restrict__ part)
{
  const int bid = blockIdx.x;
  const int b = bid & 15, chunk = bid >> 4;   // chunk 0..63
  const int pos0 = chunk << 6;
  const int tid = threadIdx.x;
  __shared__ u16 tile[8192];         // 16 KB
  __shared__ float psum[128 * 17];   // 8.7 KB
  const float* xb = x + ((size_t)b << 19) + pos0;
  const int rq = tid & 15;           // row-quad
  const int p4 = rq << 2;
  const int gci = tid >> 4;          // granule 0..15

  if (chunk == 0){                   // fused halo zeroing (disjoint from interior)
    u16* xh = xT2 + (size_t)b * XB_STRIDE;
    for (int i = tid; i < 4160; i += 256){     // 260 pos * 16 granules
      const int p = i >> 4, oct = i & 15;
      int row, col;
      if (p < 66)      { row = 0;        col = p; }
      else if (p < 132){ row = 65;       col = p - 66; }
      else if (p < 196){ row = p - 131;  col = 0; }
      else             { row = p - 195;  col = 65; }
      *(uint4*)(xh + row * XR_STRIDE + (col << 7) + (oct << 3)) =
          make_uint4(0u, 0u, 0u, 0u);
    }
  }

  {
    const int ci8 = gci << 3;
    f32x4 L[8];
    #pragma unroll
    for (int j = 0; j < 8; ++j){
      const f32x4* sp4 = (const f32x4*)(xb + ((size_t)(ci8 + j) << 12) + p4);
      L[j] = __builtin_nontemporal_load(sp4);
    }
    #pragma unroll
    for (int j = 0; j < 8; ++j)
      psum[(ci8 + j) * 17 + rq] = L[j].x + L[j].y + L[j].z + L[j].w;
    const int gs = gci ^ (rq & 7);
    const float* e = (const float*)L;
    #pragma unroll
    for (int p = 0; p < 4; ++p){
      const int row = p4 + p;
      uint4 V;
      V.x = pk2(e[0 * 4 + p], e[1 * 4 + p]);
      V.y = pk2(e[2 * 4 + p], e[3 * 4 + p]);
      V.z = pk2(e[4 * 4 + p], e[5 * 4 + p]);
      V.w = pk2(e[6 * 4 + p], e[7 * 4 + p]);
      *(uint4*)(tile + (row << 7) + (gs << 3)) = V;
    }
  }
  __syncthreads();

  if (tid < 128){
    float s = 0.f;
    #pragma unroll
    for (int j = 0; j < 16; ++j) s += psum[tid * 17 + j];
    part[(((b << 6) | chunk) << 7) + tid] = s;
  }

  u16* xo = xT2 + (size_t)b * XB_STRIDE;
  const int g = tid & 15, rb = (tid >> 4) << 2;
  #pragma unroll
  for (int r = 0; r < 4; ++r){
    const int row = rb + r;
    const int gs = g ^ ((row >> 2) & 7);
    uint4 v = *(const uint4*)(tile + (row << 7) + (gs << 3));
    const int pos = pos0 + row;
    const int h = pos >> 6, w = pos & 63;
    *(uint4*)(xo + (h + 1) * XR_STRIDE + ((w + 1) << 7) + (g << 3)) = v;
  }
}

// ---------------------------------------------------------------------------
// Kernel 2: combine + inline attn. W staging T14 reg-staged with NT loads
// (ext-vector f32x4): issue 9 NT loads -> attn compute hides latency ->
// ds_write -> barrier. grid 1024 = cp*16 + b (bid%8==b%8 homing).
// ---------------------------------------------------------------------------
__global__ __launch_bounds__(256) void combine(
    const float* __restrict__ W, const float* __restrict__ bias,
    const float* __restrict__ part, const float* __restrict__ w1,
    const float* __restrict__ w2, const float* __restrict__ b2,
    u16* __restrict__ wcomb, float* __restrict__ bcomb)
{
  __shared__ float wlds[9216];   // [k][co_l][1152]
  __shared__ float sp[128];
  __shared__ float sh[33];
  __shared__ float sat[4];
  const int bid = blockIdx.x;
  const int b = bid & 15, cp = bid >> 4;    // cp: co-pair 0..63
  const int tid = threadIdx.x;

  // issue W loads (NT, read-once stream)
  f32x4 wreg[9];
  #pragma unroll
  for (int it = 0; it < 9; ++it){
    const int G = it * 256 + tid;
    const int k = G / 576, rem = G - k * 576;
    const int co_l = rem / 288, j4 = rem - co_l * 288;
    const f32x4* src = (const f32x4*)(W + (size_t)(k * 128 + (cp << 1) + co_l) * 1152 + (j4 << 2));
    wreg[it] = __builtin_nontemporal_load(src);
  }

  // ---- inline attn[b]: pool (64 chunks) -> fc1 -> relu -> fc2 -> softmax ----
  if (tid < 128){
    const float* pb = part + (b << 13);
    float s = 0.f;
    #pragma unroll 8
    for (int c = 0; c < 64; ++c) s += pb[(c << 7) + tid];
    sp[tid] = s * (1.f / 4096.f);
  }
  __syncthreads();
  if (tid < 33){
    float h = 0.f;
    for (int ci = 0; ci < 128; ++ci) h += sp[ci] * w1[tid * 128 + ci];
    sh[tid] = fmaxf(h, 0.f);
  }
  __syncthreads();
  if (tid == 0){
    float l[4];
    #pragma unroll
    for (int t = 0; t < 4; ++t){
      float v = b2[t];
      for (int j = 0; j < 33; ++j) v += sh[j] * w2[t * 33 + j];
      l[t] = v * (1.f / 30.f);
    }
    float m = fmaxf(fmaxf(l[0], l[1]), fmaxf(l[2], l[3]));
    float e0 = __expf(l[0] - m), e1 = __expf(l[1] - m);
    float e2 = __expf(l[2] - m), e3 = __expf(l[3] - m);
    float inv = 1.f / (e0 + e1 + e2 + e3);
    sat[0] = e0 * inv; sat[1] = e1 * inv; sat[2] = e2 * inv; sat[3] = e3 * inv;
  }

  // write-late: park W regs in LDS (same G -> offset map as before)
  #pragma unroll
  for (int it = 0; it < 9; ++it){
    const int G = it * 256 + tid;
    *(f32x4*)((char*)wlds + (G << 4)) = wreg[it];
  }
  __syncthreads();
  const float a0 = sat[0], a1 = sat[1], a2 = sat[2], a3 = sat[3];

  if (tid < 2){
    const int co = (cp << 1) + tid;
    bcomb[(b << 7) + co] = a0 * bias[co] + a1 * bias[128 + co]
                         + a2 * bias[256 + co] + a3 * bias[384 + co];
  }

  u16* wob = wcomb + (size_t)b * 147456;
  for (int gi = tid; gi < 288; gi += 256){  // 2co * 9tap * (4q*4g) granules
    const int co_l = gi / 144;
    const int r = gi - co_l * 144;
    const int tap = r >> 4;
    const int gg = r & 15;
    const int q = gg >> 2, g = gg & 3;
    const int co = (cp << 1) + co_l;
    union { u16 h[8]; uint4 v; } pk;
    #pragma unroll
    for (int e = 0; e < 8; ++e){
      const int ci = (q << 5) + (g << 3) + e;
      const int j = ci * 9 + tap;
      float s = a0 * wlds[co_l * 1152 + j]        + a1 * wlds[2304 + co_l * 1152 + j]
              + a2 * wlds[4608 + co_l * 1152 + j] + a3 * wlds[6912 + co_l * 1152 + j];
      pk.h[e] = f2bf(s);
    }
    *(uint4*)(wob + (((tap << 2) + q) << 12) + (co << 5) + (g << 3)) = pk.v;
  }
}

// ---------------------------------------------------------------------------
// Kernel 3: ci-quarter implicit GEMM, T4 counted-vmcnt pipeline + raw
// barriers; s_setprio removed (T5 null on non-8-phase GEMM, m190).
// 36 steps; W: 3 x 8KB bufs staged 2 ahead, vmcnt(2). LDS 41472B.
// grid 512 x 256 thr (4 waves), b homed to XCD b%8.
// ---------------------------------------------------------------------------
__global__ __launch_bounds__(256, 2) void conv_mfma(
    const u16* __restrict__ xT2, const u16* __restrict__ wcomb,
    const float* __restrict__ bcomb, float* __restrict__ out)
{
  extern __shared__ char smem[];
  u16* s_x = (u16*)smem;               // [4row][66col][4oct][8ci] = 16896B
  u16* s_w = (u16*)(smem + 16896);     // 3 bufs x 4096 u16 (8KB slabs)

  const int tid = threadIdx.x;
  const int lane = tid & 63, wid = tid >> 6;
  const int wr = wid & 1, wcv = wid >> 1;    // wr: h-row, wcv: co-half
  const int l15 = lane & 15, hi = lane >> 4;

  const int bid = blockIdx.x;
  const int b = bid & 15;                    // bid%8 == b%8 (L2 homing)
  const int h0 = (bid >> 4) << 1;            // 2 output rows

  const u16* Abase = wcomb + (size_t)b * 147456;
  const u16* Xbase = xT2 + (size_t)b * XB_STRIDE;

#define STAGE_X(Q) { \
    _Pragma("unroll") \
    for (int _it = 0; _it < 5; ++_it){ \
      const int _G = _it * 256 + tid; \
      if (_it < 4 || _G < 1056){ \
        const int _oct = _G & 3, _t = _G >> 2; \
        const int _col = _t % 66, _row = _t / 66; \
        const u16* _src = Xbase + (h0 + _row) * XR_STRIDE + (_col << 7) \
                        + ((Q) << 5) + (_oct << 3); \
        GLD_LDS(_src, s_x + (_G << 3)); \
      } \
    } }

#define STAGE_W(Q, TAP, BUF) { \
    const u16* _As = Abase + ((((TAP) << 2) + (Q)) << 12); \
    u16* _sw = s_w + (BUF) * 4096; \
    GLD_LDS(_As + (tid << 3), _sw + (tid << 3)); \
    GLD_LDS(_As + ((tid + 256) << 3), _sw + ((tid + 256) << 3)); }

#define COMPUTE(TAP, BUF) { \
    const int _dh = (TAP) / 3, _dw = (TAP) - 3 * (_dh); \
    const u16* _sw = s_w + (BUF) * 4096; \
    short8 _af[4], _bf[4]; \
    _Pragma("unroll") \
    for (int _a = 0; _a < 4; ++_a){ \
      const int _co = (wcv << 6) + (_a << 4) + l15; \
      _af[_a] = *(const short8*)(_sw + (_co << 5) + (hi << 3)); \
    } \
    _Pragma("unroll") \
    for (int _p = 0; _p < 4; ++_p){ \
      const int _col = l15 + _dw + (_p << 4); \
      _bf[_p] = *(const short8*)(s_x + (((wr + _dh) * 66 + _col) << 5) + (hi << 3)); \
    } \
    _Pragma("unroll") \
    for (int _a = 0; _a < 4; ++_a) \
      _Pragma("unroll") \
      for (int _p = 0; _p < 4; ++_p) \
        acc[_a][_p] = __builtin_amdgcn_mfma_f32_16x16x32_bf16(_af[_a], _bf[_p], acc[_a][_p], 0, 0, 0); }

  f32x4 acc[4][4] = {};

  // prologue: X(0) + W slabs for steps 0,1 in flight
  STAGE_X(0);
  STAGE_W(0, 0, 0);
  STAGE_W(0, 1, 1);

  for (int q = 0; q < 4; ++q){
    #pragma unroll
    for (int tap = 0; tap < 9; ++tap){
      // wait: slab(step) [+ X at q boundary] done; leave newest 2 in flight
      if (tap == 8 && q == 3){ WAIT_VM(0); } else { WAIT_VM(2); }
      BAR;
      // prefetch slab(step+2) into the buffer freed by compute(step-1)
      if (tap <= 6){
        STAGE_W(q, tap + 2, (tap + 2) % 3);
      } else if (tap == 7){
        if (q < 3){ STAGE_W(q + 1, 0, 0); }
      }
      COMPUTE(tap, tap % 3);
      if (tap == 8 && q < 3){
        BAR;                   // all waves done reading s_x(q)
        STAGE_X(q + 1);        // 9 loads; waited at next step's vmcnt(2)
        STAGE_W(q + 1, 1, 1);  // slab(step+2), buf (8+2)%3 = 1
      }
    }
  }

#undef COMPUTE
#undef STAGE_W
#undef STAGE_X

  // ---- epilogue: C/D col=l15 (w), row=hi*4+r (co). NT stores. ----
  const int hrow = h0 + wr;
  float* ob = out + ((size_t)b << 19) + (hrow << 6) + l15;
  #pragma unroll
  for (int a = 0; a < 4; ++a){
    const int co0 = (wcv << 6) + (a << 4) + (hi << 2);
    #pragma unroll
    for (int r = 0; r < 4; ++r){
      const float bc = bcomb[(b << 7) + co0 + r];
      float* op = ob + (size_t)(co0 + r) * 4096;
      #pragma unroll
      for (int p = 0; p < 4; ++p)
        __builtin_nontemporal_store(acc[a][p][r] + bc, op + (p << 4));
    }
  }
}

// ---------------------------------------------------------------------------
extern "C" void kernel_launch(void* const* d_in, const int* in_sizes, int n_in,
                              void* d_out, int out_size, void* d_ws, size_t ws_size,
                              hipStream_t stream)
{
  const float* x    = (const float*)d_in[0];
  const float* W    = (const float*)d_in[1];
  const float* bias = (const float*)d_in[2];
  const float* w1   = (const float*)d_in[3];
  const float* w2   = (const float*)d_in[4];
  const float* b2   = (const float*)d_in[5];
  float* out = (float*)d_out;

  char* ws = (char*)d_ws;
  float* part  = (float*)(ws);               // 16*64*128*4 = 524288 B
  float* bcomb = (float*)(ws + 524288);      // 8192 B
  u16*   xT2   = (u16*)  (ws + 532480);      // 17,842,176 B
  u16*   wcomb = (u16*)  (ws + 18374656);    // 4,718,592 B (end ~23.1 MB)

  xpose_pool<<<1024, 256, 0, stream>>>(x, xT2, part);
  combine<<<1024, 256, 0, stream>>>(W, bias, part, w1, w2, b2, wcomb, bcomb);

  (void)hipFuncSetAttribute(reinterpret_cast<const void*>(conv_mfma),
                            hipFuncAttributeMaxDynamicSharedMemorySize, 41472);
  conv_mfma<<<512, 256, 41472, stream>>>(xT2, wcomb, bcomb, out);
}

// Round 15
// 49.045 us; speedup vs baseline: 1.0675x; 1.0675x over previous
//
#include <hip/hip_runtime.h>
#include <cstdint>
#include <cstddef>

typedef unsigned short u16;
typedef __attribute__((ext_vector_type(8))) short short8;
typedef __attribute__((ext_vector_type(4))) float f32x4;

__device__ __forceinline__ u16 f2bf(float f){
  union { float f; unsigned u; } c; c.f = f;
  unsigned u = c.u;
  u += 0x7fffu + ((u >> 16) & 1u);   // RNE
  return (u16)(u >> 16);
}
__device__ __forceinline__ unsigned pk2(float a, float b){
  union { float f; unsigned u; } ca, cb; ca.f = a; cb.f = b;
  return ((ca.u + 0x8000u) >> 16) | ((cb.u + 0x8000u) & 0xFFFF0000u);
}

// xT2 layout: [b][row 0..65][col 0..65][128ci] bf16, interior at (h+1, w+1).
#define XB_STRIDE 557568   // 66*66*128 (u16 elements)
#define XR_STRIDE 8448     // 66*128

// wcomb layout (u16): b*147456 + ((tap*4+q)<<12) + (co<<5) + ciq
//   where ci = q*32 + ciq. One (tap,q) slab = 128co x 32ci = 8KB, linear.

// direct-to-LDS 16B async copy
#define GLD_LDS(gsrc, ldst) \
  __builtin_amdgcn_global_load_lds((const __attribute__((address_space(1))) void*)(gsrc), \
                                   (__attribute__((address_space(3))) void*)(ldst), 16, 0, 0)

// raw barrier WITHOUT the implicit vmcnt(0) drain of __syncthreads()
#define BAR { asm volatile("s_waitcnt lgkmcnt(0)" ::: "memory"); \
              __builtin_amdgcn_s_barrier(); }
#define WAIT_VM(N) asm volatile("s_waitcnt vmcnt(" #N ")" ::: "memory")

// ---------------------------------------------------------------------------
// Kernel 1 (r12 version): transpose x -> padded xT2 bf16 + SE pool partials.
// grid 1024 (4 blocks/CU), b = bid&15 (bid%8==b%8 homing).
// ---------------------------------------------------------------------------
__global__ __launch_bounds__(256) void xpose_pool(
    const float* __restrict__ x, u16* __restrict__ xT2, float* __restrict__ part)
{
  const int bid = blockIdx.x;
  const int b = bid & 15, chunk = bid >> 4;   // chunk 0..63
  const int pos0 = chunk << 6;
  const int tid = threadIdx.x;
  __shared__ u16 tile[8192];         // 16 KB
  __shared__ float psum[128 * 17];   // 8.7 KB
  const float* xb = x + ((size_t)b << 19) + pos0;
  const int rq = tid & 15;           // row-quad
  const int p4 = rq << 2;
  const int gci = tid >> 4;          // granule 0..15

  if (chunk == 0){                   // fused halo zeroing (disjoint from interior)
    u16* xh = xT2 + (size_t)b * XB_STRIDE;
    for (int i = tid; i < 4160; i += 256){     // 260 pos * 16 granules
      const int p = i >> 4, oct = i & 15;
      int row, col;
      if (p < 66)      { row = 0;        col = p; }
      else if (p < 132){ row = 65;       col = p - 66; }
      else if (p < 196){ row = p - 131;  col = 0; }
      else             { row = p - 195;  col = 65; }
      *(uint4*)(xh + row * XR_STRIDE + (col << 7) + (oct << 3)) =
          make_uint4(0u, 0u, 0u, 0u);
    }
  }

  {
    const int ci8 = gci << 3;
    float4 L[8];
    #pragma unroll
    for (int j = 0; j < 8; ++j)
      L[j] = *(const float4*)(xb + ((size_t)(ci8 + j) << 12) + p4);
    #pragma unroll
    for (int j = 0; j < 8; ++j)
      psum[(ci8 + j) * 17 + rq] = L[j].x + L[j].y + L[j].z + L[j].w;
    const int gs = gci ^ (rq & 7);
    const float* e = (const float*)L;
    #pragma unroll
    for (int p = 0; p < 4; ++p){
      const int row = p4 + p;
      uint4 V;
      V.x = pk2(e[0 * 4 + p], e[1 * 4 + p]);
      V.y = pk2(e[2 * 4 + p], e[3 * 4 + p]);
      V.z = pk2(e[4 * 4 + p], e[5 * 4 + p]);
      V.w = pk2(e[6 * 4 + p], e[7 * 4 + p]);
      *(uint4*)(tile + (row << 7) + (gs << 3)) = V;
    }
  }
  __syncthreads();

  if (tid < 128){
    float s = 0.f;
    #pragma unroll
    for (int j = 0; j < 16; ++j) s += psum[tid * 17 + j];
    part[(((b << 6) | chunk) << 7) + tid] = s;
  }

  u16* xo = xT2 + (size_t)b * XB_STRIDE;
  const int g = tid & 15, rb = (tid >> 4) << 2;
  #pragma unroll
  for (int r = 0; r < 4; ++r){
    const int row = rb + r;
    const int gs = g ^ ((row >> 2) & 7);
    uint4 v = *(const uint4*)(tile + (row << 7) + (gs << 3));
    const int pos = pos0 + row;
    const int h = pos >> 6, w = pos & 63;
    *(uint4*)(xo + (h + 1) * XR_STRIDE + ((w + 1) << 7) + (g << 3)) = v;
  }
}

// ---------------------------------------------------------------------------
// Kernel 2 (r12 version): combine + inline attn, W staged via gld_lds under
// the attn compute. grid 1024 = cp*16 + b (bid%8==b%8 homing).
// ---------------------------------------------------------------------------
__global__ __launch_bounds__(256) void combine(
    const float* __restrict__ W, const float* __restrict__ bias,
    const float* __restrict__ part, const float* __restrict__ w1,
    const float* __restrict__ w2, const float* __restrict__ b2,
    u16* __restrict__ wcomb, float* __restrict__ bcomb)
{
  __shared__ float wlds[9216];   // [k][co_l][1152]
  __shared__ float sp[128];
  __shared__ float sh[33];
  __shared__ float sat[4];
  const int bid = blockIdx.x;
  const int b = bid & 15, cp = bid >> 4;    // cp: co-pair 0..63
  const int tid = threadIdx.x;

  #pragma unroll
  for (int it = 0; it < 9; ++it){
    const int G = it * 256 + tid;
    const int k = G / 576, rem = G - k * 576;
    const int co_l = rem / 288, j4 = rem - co_l * 288;
    const float* src = W + (size_t)(k * 128 + (cp << 1) + co_l) * 1152 + (j4 << 2);
    GLD_LDS(src, (char*)wlds + (G << 4));
  }

  // ---- inline attn[b]: pool (64 chunks) -> fc1 -> relu -> fc2 -> softmax ----
  if (tid < 128){
    const float* pb = part + (b << 13);
    float s = 0.f;
    #pragma unroll 8
    for (int c = 0; c < 64; ++c) s += pb[(c << 7) + tid];
    sp[tid] = s * (1.f / 4096.f);
  }
  __syncthreads();
  if (tid < 33){
    float h = 0.f;
    for (int ci = 0; ci < 128; ++ci) h += sp[ci] * w1[tid * 128 + ci];
    sh[tid] = fmaxf(h, 0.f);
  }
  __syncthreads();
  if (tid == 0){
    float l[4];
    #pragma unroll
    for (int t = 0; t < 4; ++t){
      float v = b2[t];
      for (int j = 0; j < 33; ++j) v += sh[j] * w2[t * 33 + j];
      l[t] = v * (1.f / 30.f);
    }
    float m = fmaxf(fmaxf(l[0], l[1]), fmaxf(l[2], l[3]));
    float e0 = __expf(l[0] - m), e1 = __expf(l[1] - m);
    float e2 = __expf(l[2] - m), e3 = __expf(l[3] - m);
    float inv = 1.f / (e0 + e1 + e2 + e3);
    sat[0] = e0 * inv; sat[1] = e1 * inv; sat[2] = e2 * inv; sat[3] = e3 * inv;
  }
  asm volatile("s_waitcnt vmcnt(0)" ::: "memory");
  __syncthreads();
  const float a0 = sat[0], a1 = sat[1], a2 = sat[2], a3 = sat[3];

  if (tid < 2){
    const int co = (cp << 1) + tid;
    bcomb[(b << 7) + co] = a0 * bias[co] + a1 * bias[128 + co]
                         + a2 * bias[256 + co] + a3 * bias[384 + co];
  }

  u16* wob = wcomb + (size_t)b * 147456;
  for (int gi = tid; gi < 288; gi += 256){  // 2co * 9tap * (4q*4g) granules
    const int co_l = gi / 144;
    const int r = gi - co_l * 144;
    const int tap = r >> 4;
    const int gg = r & 15;
    const int q = gg >> 2, g = gg & 3;
    const int co = (cp << 1) + co_l;
    union { u16 h[8]; uint4 v; } pk;
    #pragma unroll
    for (int e = 0; e < 8; ++e){
      const int ci = (q << 5) + (g << 3) + e;
      const int j = ci * 9 + tap;
      float s = a0 * wlds[co_l * 1152 + j]        + a1 * wlds[2304 + co_l * 1152 + j]
              + a2 * wlds[4608 + co_l * 1152 + j] + a3 * wlds[6912 + co_l * 1152 + j];
      pk.h[e] = f2bf(s);
    }
    *(uint4*)(wob + (((tap << 2) + q) << 12) + (co << 5) + (g << 3)) = pk.v;
  }
}

// ---------------------------------------------------------------------------
// Kernel 3 (v13): r12's counted-vmcnt pipeline + setprio, with DOUBLE-
// BUFFERED s_x: X(q+1) issued at tap5 into the inactive buffer, waited
// implicitly by tap8's vmcnt(2) (~3 steps of cover). Queue bookkeeping:
// tap6/7 tops (q<3) wait vmcnt(11) = current W slab done, W(next)+X(9)
// remain in flight. Removes 3 boundary barriers + 3 exposed X restages.
// LDS 2*16896 + 3*8192 = 58368B -> 2 blocks/CU. grid 512 x 256 thr.
// ---------------------------------------------------------------------------
__global__ __launch_bounds__(256, 2) void conv_mfma(
    const u16* __restrict__ xT2, const u16* __restrict__ wcomb,
    const float* __restrict__ bcomb, float* __restrict__ out)
{
  extern __shared__ char smem[];
  u16* s_x = (u16*)smem;               // 2 bufs x [4row][66col][4oct][8ci] (16896B)
  u16* s_w = (u16*)(smem + 33792);     // 3 bufs x 4096 u16 (8KB slabs)

  const int tid = threadIdx.x;
  const int lane = tid & 63, wid = tid >> 6;
  const int wr = wid & 1, wcv = wid >> 1;    // wr: h-row, wcv: co-half
  const int l15 = lane & 15, hi = lane >> 4;

  const int bid = blockIdx.x;
  const int b = bid & 15;                    // bid%8 == b%8 (L2 homing)
  const int h0 = (bid >> 4) << 1;            // 2 output rows

  const u16* Abase = wcomb + (size_t)b * 147456;
  const u16* Xbase = xT2 + (size_t)b * XB_STRIDE;

#define STAGE_X(Q) { \
    u16* _sx = s_x + ((Q) & 1) * 8448; \
    _Pragma("unroll") \
    for (int _it = 0; _it < 5; ++_it){ \
      const int _G = _it * 256 + tid; \
      if (_it < 4 || _G < 1056){ \
        const int _oct = _G & 3, _t = _G >> 2; \
        const int _col = _t % 66, _row = _t / 66; \
        const u16* _src = Xbase + (h0 + _row) * XR_STRIDE + (_col << 7) \
                        + ((Q) << 5) + (_oct << 3); \
        GLD_LDS(_src, _sx + (_G << 3)); \
      } \
    } }

#define STAGE_W(Q, TAP, BUF) { \
    const u16* _As = Abase + ((((TAP) << 2) + (Q)) << 12); \
    u16* _sw = s_w + (BUF) * 4096; \
    GLD_LDS(_As + (tid << 3), _sw + (tid << 3)); \
    GLD_LDS(_As + ((tid + 256) << 3), _sw + ((tid + 256) << 3)); }

#define COMPUTE(Q, TAP, BUF) { \
    const int _dh = (TAP) / 3, _dw = (TAP) - 3 * (_dh); \
    const u16* _sw = s_w + (BUF) * 4096; \
    const u16* _sx = s_x + ((Q) & 1) * 8448; \
    short8 _af[4], _bf[4]; \
    _Pragma("unroll") \
    for (int _a = 0; _a < 4; ++_a){ \
      const int _co = (wcv << 6) + (_a << 4) + l15; \
      _af[_a] = *(const short8*)(_sw + (_co << 5) + (hi << 3)); \
    } \
    _Pragma("unroll") \
    for (int _p = 0; _p < 4; ++_p){ \
      const int _col = l15 + _dw + (_p << 4); \
      _bf[_p] = *(const short8*)(_sx + (((wr + _dh) * 66 + _col) << 5) + (hi << 3)); \
    } \
    _Pragma("unroll") \
    for (int _a = 0; _a < 4; ++_a) \
      _Pragma("unroll") \
      for (int _p = 0; _p < 4; ++_p) \
        acc[_a][_p] = __builtin_amdgcn_mfma_f32_16x16x32_bf16(_af[_a], _bf[_p], acc[_a][_p], 0, 0, 0); }

  f32x4 acc[4][4] = {};

  // prologue: X(0) + W slabs for steps 0,1 in flight
  STAGE_X(0);
  STAGE_W(0, 0, 0);
  STAGE_W(0, 1, 1);

  for (int q = 0; q < 4; ++q){
    #pragma unroll
    for (int tap = 0; tap < 9; ++tap){
      // waits (hand-verified queue accounting, see header comment)
      if (q == 3 && tap == 8)                  { WAIT_VM(0); }
      else if (q < 3 && (tap == 6 || tap == 7)){ WAIT_VM(11); }
      else                                     { WAIT_VM(2); }
      BAR;
      // W prefetch 2 steps ahead
      if (tap <= 6){
        STAGE_W(q, tap + 2, (tap + 2) % 3);
      } else if (tap == 7){
        if (q < 3){ STAGE_W(q + 1, 0, 0); }
      } else { // tap == 8
        if (q < 3){ STAGE_W(q + 1, 1, 1); }
      }
      // X prefetch for next quarter into inactive buffer (no hazard)
      if (tap == 5 && q < 3){ STAGE_X(q + 1); }
      __builtin_amdgcn_s_setprio(1);
      COMPUTE(q, tap, tap % 3);
      __builtin_amdgcn_s_setprio(0);
    }
  }

#undef COMPUTE
#undef STAGE_W
#undef STAGE_X

  // ---- epilogue: C/D col=l15 (w), row=hi*4+r (co). NT stores. ----
  const int hrow = h0 + wr;
  float* ob = out + ((size_t)b << 19) + (hrow << 6) + l15;
  #pragma unroll
  for (int a = 0; a < 4; ++a){
    const int co0 = (wcv << 6) + (a << 4) + (hi << 2);
    #pragma unroll
    for (int r = 0; r < 4; ++r){
      const float bc = bcomb[(b << 7) + co0 + r];
      float* op = ob + (size_t)(co0 + r) * 4096;
      #pragma unroll
      for (int p = 0; p < 4; ++p)
        __builtin_nontemporal_store(acc[a][p][r] + bc, op + (p << 4));
    }
  }
}

// ---------------------------------------------------------------------------
extern "C" void kernel_launch(void* const* d_in, const int* in_sizes, int n_in,
                              void* d_out, int out_size, void* d_ws, size_t ws_size,
                              hipStream_t stream)
{
  const float* x    = (const float*)d_in[0];
  const float* W    = (const float*)d_in[1];
  const float* bias = (const float*)d_in[2];
  const float* w1   = (const float*)d_in[3];
  const float* w2   = (const float*)d_in[4];
  const float* b2   = (const float*)d_in[5];
  float* out = (float*)d_out;

  char* ws = (char*)d_ws;
  float* part  = (float*)(ws);               // 16*64*128*4 = 524288 B
  float* bcomb = (float*)(ws + 524288);      // 8192 B
  u16*   xT2   = (u16*)  (ws + 532480);      // 17,842,176 B
  u16*   wcomb = (u16*)  (ws + 18374656);    // 4,718,592 B (end ~23.1 MB)

  xpose_pool<<<1024, 256, 0, stream>>>(x, xT2, part);
  combine<<<1024, 256, 0, stream>>>(W, bias, part, w1, w2, b2, wcomb, bcomb);

  (void)hipFuncSetAttribute(reinterpret_cast<const void*>(conv_mfma),
                            hipFuncAttributeMaxDynamicSharedMemorySize, 58368);
  conv_mfma<<<512, 256, 58368, stream>>>(xT2, wcomb, bcomb, out);
}